// Round 2
// baseline (238.649 us; speedup 1.0000x reference)
//
#include <hip/hip_runtime.h>
#include <cfloat>

// ---------------------------------------------------------------------------
// VQ-VAE vector quantizer forward (MI355X / gfx950)
//   x        [32][64][64][64] f32   (B, D, H, W)
//   codebook [1024][64] f32
// out: x_q transposed back to [B,D,H,W] (8388608 f32)  +  loss scalar (1 f32)
//
// argmin_k ||x - c_k||^2  ==  argmax_k (x . c_k - ||c_k||^2/2)
// loss = 1.25 * mean(||x - c_idx||^2) ; SSE(pos) = ||x||^2 - 2 * s_best
//
// R2: K-split — 1 block (4 waves) per (b,h) row; each wave scans 16 of the
// 64 code tiles; LDS merge. 8192 waves = 8/SIMD (was 2/SIMD, 19% occupancy).
// ---------------------------------------------------------------------------

#define DD   64
#define HHWW 4096          // H*W
#define KC   1024
#define NBLK  2048         // one block per (b,h) row
#define NPOSD 8388608.0f   // N * D

typedef __bf16  bf16x8 __attribute__((ext_vector_type(8)));
typedef unsigned short u16x8 __attribute__((ext_vector_type(8)));
typedef float   f32x4  __attribute__((ext_vector_type(4)));

__device__ __forceinline__ unsigned short bf16_bits(float f) {
  unsigned u = __float_as_uint(f);
  return (unsigned short)((u + 0x7FFFu + ((u >> 16) & 1u)) >> 16);  // RNE
}

// --- precompute: fragment-ordered bf16 codebook, -||c||^2/2, codebook^T -----
__global__ __launch_bounds__(256) void vq_pre(
    const float* __restrict__ cb,          // [1024][64]
    unsigned short* __restrict__ cb_frag,  // [tile=64][kk=2][lane=64][e=8]
    float* __restrict__ hneg,              // [1024]
    float* __restrict__ cbT)               // [64][1024]
{
  int k = blockIdx.x * 256 + threadIdx.x;
  if (k >= KC) return;
  float c[DD];
  float sum = 0.f;
#pragma unroll
  for (int d = 0; d < DD; ++d) { c[d] = cb[k * DD + d]; sum += c[d] * c[d]; }
  hneg[k] = -0.5f * sum;
#pragma unroll
  for (int d = 0; d < DD; ++d) cbT[d * KC + k] = c[d];
  int t = k >> 4, l15 = k & 15;
#pragma unroll
  for (int kk = 0; kk < 2; ++kk)
#pragma unroll
    for (int g = 0; g < 4; ++g)
#pragma unroll
      for (int e = 0; e < 8; ++e)
        cb_frag[(((t * 2 + kk) * 64) + (g * 16 + l15)) * 8 + e] =
            bf16_bits(c[kk * 32 + g * 8 + e]);
}

// --- main: fused distance-GEMM + argmin + loss partial + output write ------
__global__ __launch_bounds__(256, 8) void vq_main(
    const float* __restrict__ x,
    const unsigned short* __restrict__ cb_frag,
    const float* __restrict__ hneg,
    const float* __restrict__ cbT,
    float* __restrict__ out,
    float* __restrict__ partials)
{
  __shared__ float xsq_lds[64];
  __shared__ float cand_s[4][64];
  __shared__ int   cand_c[4][64];
  __shared__ int   idx_lds[64];

  const int tid  = threadIdx.x;
  const int wv   = tid >> 6;
  const int lane = tid & 63;
  const int l15  = lane & 15;
  const int g    = lane >> 4;

  const int row = blockIdx.x;            // global (b,h) row, 0..2047
  const int b   = row >> 6;
  const int h   = row & 63;
  const float* xb = x + (size_t)b * DD * HHWW + h * 64;  // xb[d*4096 + w]

  // ---- load A fragments (x, bf16) + per-position ||x||^2 (all waves same) --
  // A layout convention (matches B): row i = lane&15, k = kk*32+(lane>>4)*8+e.
  bf16x8 afrag[4][2];
#pragma unroll
  for (int pt = 0; pt < 4; ++pt) {
    const int w = pt * 16 + l15;
    float s = 0.f;
#pragma unroll
    for (int kk = 0; kk < 2; ++kk) {
      const int dbase = kk * 32 + g * 8;
      u16x8 f;
#pragma unroll
      for (int e = 0; e < 8; ++e) {
        float v = xb[(size_t)(dbase + e) * HHWW + w];
        s += v * v;
        f[e] = bf16_bits(v);
      }
      afrag[pt][kk] = __builtin_bit_cast(bf16x8, f);
    }
    s += __shfl_xor(s, 16, 64);
    s += __shfl_xor(s, 32, 64);
    if (wv == 0 && g == 0) xsq_lds[pt * 16 + l15] = s;  // full 64-dim sum
  }

  // ---- scan this wave's 16 code tiles ----
  float best_s[4][4];
  int   best_c[4][4];
#pragma unroll
  for (int pt = 0; pt < 4; ++pt)
#pragma unroll
    for (int r = 0; r < 4; ++r) { best_s[pt][r] = -FLT_MAX; best_c[pt][r] = 0; }

  for (int t = 0; t < 16; ++t) {
    const int tc = wv * 16 + t;
    const float mh = hneg[tc * 16 + l15];          // folded into C-init
    const bf16x8* bptr = (const bf16x8*)(cb_frag + (size_t)tc * 2 * 64 * 8);
    const bf16x8 b0 = bptr[lane];       // kk=0, coalesced 1KB/wave
    const bf16x8 b1 = bptr[64 + lane];  // kk=1
    f32x4 acc[4];
#pragma unroll
    for (int pt = 0; pt < 4; ++pt) acc[pt] = (f32x4){mh, mh, mh, mh};
#pragma unroll
    for (int pt = 0; pt < 4; ++pt)
      acc[pt] = __builtin_amdgcn_mfma_f32_16x16x32_bf16(afrag[pt][0], b0, acc[pt], 0, 0, 0);
#pragma unroll
    for (int pt = 0; pt < 4; ++pt)
      acc[pt] = __builtin_amdgcn_mfma_f32_16x16x32_bf16(afrag[pt][1], b1, acc[pt], 0, 0, 0);
    const int code = tc * 16 + l15;
#pragma unroll
    for (int pt = 0; pt < 4; ++pt)
#pragma unroll
      for (int r = 0; r < 4; ++r) {
        float v = acc[pt][r];          // C/D: col=lane&15(code), row=g*4+r(pos)
        if (v > best_s[pt][r]) { best_s[pt][r] = v; best_c[pt][r] = code; }
      }
  }

  // ---- cross-lane argmax over the 16 code columns (lane&15) ----
#pragma unroll
  for (int pt = 0; pt < 4; ++pt)
#pragma unroll
    for (int r = 0; r < 4; ++r) {
      float s = best_s[pt][r];
      int   c = best_c[pt][r];
#pragma unroll
      for (int m = 1; m < 16; m <<= 1) {
        float so = __shfl_xor(s, m, 64);
        int   co = __shfl_xor(c, m, 64);
        if (so > s || (so == s && co < c)) { s = so; c = co; }
      }
      if (l15 == 0) {
        int p = pt * 16 + g * 4 + r;
        cand_s[wv][p] = s;
        cand_c[wv][p] = c;
      }
    }

  __syncthreads();

  // ---- cross-wave merge (4 candidates per position) + loss partial ----
  if (tid < 64) {
    float s = cand_s[0][tid];
    int   c = cand_c[0][tid];
#pragma unroll
    for (int w = 1; w < 4; ++w) {
      float so = cand_s[w][tid];
      int   co = cand_c[w][tid];
      if (so > s || (so == s && co < c)) { s = so; c = co; }
    }
    idx_lds[tid] = c;
    float sse = xsq_lds[tid] - 2.0f * s;
#pragma unroll
    for (int m = 1; m < 64; m <<= 1) sse += __shfl_xor(sse, m, 64);
    if (tid == 0) partials[blockIdx.x] = sse;
  }

  __syncthreads();

  // ---- write quantized output (transposed, d-rows split across waves) ----
  const int myidx = idx_lds[lane];     // position w = lane
  float* ob = out + (size_t)b * DD * HHWW + h * 64;
#pragma unroll
  for (int dd = 0; dd < 16; ++dd) {
    const int d = wv * 16 + dd;
    ob[(size_t)d * HHWW + lane] = cbT[d * KC + myidx];
  }
}

// --- final loss reduce ------------------------------------------------------
__global__ __launch_bounds__(256) void vq_loss(
    const float* __restrict__ partials, float* __restrict__ loss_out)
{
  __shared__ float sred[4];
  int tid = threadIdx.x;
  float s = 0.f;
  for (int i = tid; i < NBLK; i += 256) s += partials[i];
#pragma unroll
  for (int m = 1; m < 64; m <<= 1) s += __shfl_xor(s, m, 64);
  if ((tid & 63) == 0) sred[tid >> 6] = s;
  __syncthreads();
  if (tid == 0)
    loss_out[0] = (sred[0] + sred[1] + sred[2] + sred[3]) * (1.25f / NPOSD);
}

extern "C" void kernel_launch(void* const* d_in, const int* in_sizes, int n_in,
                              void* d_out, int out_size, void* d_ws, size_t ws_size,
                              hipStream_t stream) {
  const float* x  = (const float*)d_in[0];
  const float* cb = (const float*)d_in[1];
  float* out      = (float*)d_out;
  float* loss_out = out + 8388608;

  char* ws = (char*)d_ws;
  unsigned short* cb_frag = (unsigned short*)(ws);      // 131072 B
  float* hneg     = (float*)(ws + 131072);              //   4096 B
  float* cbT      = (float*)(ws + 135168);              // 262144 B
  float* partials = (float*)(ws + 397312);              //   8192 B

  vq_pre <<<4,    256, 0, stream>>>(cb, cb_frag, hneg, cbT);
  vq_main<<<NBLK, 256, 0, stream>>>(x, cb_frag, hneg, cbT, out, partials);
  vq_loss<<<1,    256, 0, stream>>>(partials, loss_out);
}

// Round 3
// 60.013 us; speedup vs baseline: 3.9766x; 3.9766x over previous
//
#include <hip/hip_runtime.h>
#include <cfloat>

// ---------------------------------------------------------------------------
// VQ-VAE vector quantizer forward (MI355X / gfx950)
//   x        [32][64][64][64] f32   (B, D, H, W)
//   codebook [1024][64] f32
// out: x_q transposed back to [B,D,H,W] (8388608 f32)  +  loss scalar (1 f32)
//
// argmin_k ||x - c_k||^2  ==  argmax_k (x . c_k - ||c_k||^2/2)
// loss = 1.25 * mean(||x - c_idx||^2) ; SSE(pos) = ||x||^2 - 2 * s_best
//
// R3: position-split. Wave = (row, 16 positions), scans all 1024 codes.
// 8192 waves = 8/SIMD with only ~48 VGPRs of state (R2's reg-cap spill
// disaster avoided: no launch_bounds cap). Block (4 waves, one row) shares
// B-tiles via double-buffered LDS staging (global_load_lds, 2 tiles/phase).
// ---------------------------------------------------------------------------

#define DD   64
#define HHWW 4096          // H*W
#define KC   1024
#define NBLK  2048         // one block per (b,h) row
#define NPOSD 8388608.0f   // N * D

typedef __bf16  bf16x8 __attribute__((ext_vector_type(8)));
typedef unsigned short u16x8 __attribute__((ext_vector_type(8)));
typedef float   f32x4  __attribute__((ext_vector_type(4)));

__device__ __forceinline__ unsigned short bf16_bits(float f) {
  unsigned u = __float_as_uint(f);
  return (unsigned short)((u + 0x7FFFu + ((u >> 16) & 1u)) >> 16);  // RNE
}

// global->LDS direct copy, 16B per lane. ldst must be wave-uniform; HW adds
// lane*16. gsrc is per-lane.
__device__ __forceinline__ void gload_lds16(const void* gsrc, void* ldst) {
  __builtin_amdgcn_global_load_lds(
      (const __attribute__((address_space(1))) unsigned int*)gsrc,
      (__attribute__((address_space(3))) unsigned int*)ldst, 16, 0, 0);
}

// --- precompute: fragment-ordered bf16 codebook, -||c||^2/2, codebook^T -----
__global__ __launch_bounds__(256) void vq_pre(
    const float* __restrict__ cb,          // [1024][64]
    unsigned short* __restrict__ cb_frag,  // [tile=64][kk=2][lane=64][e=8]
    float* __restrict__ hneg,              // [1024]
    float* __restrict__ cbT)               // [64][1024]
{
  int k = blockIdx.x * 256 + threadIdx.x;
  if (k >= KC) return;
  float c[DD];
  float sum = 0.f;
#pragma unroll
  for (int d = 0; d < DD; ++d) { c[d] = cb[k * DD + d]; sum += c[d] * c[d]; }
  hneg[k] = -0.5f * sum;
#pragma unroll
  for (int d = 0; d < DD; ++d) cbT[d * KC + k] = c[d];
  int t = k >> 4, l15 = k & 15;
#pragma unroll
  for (int kk = 0; kk < 2; ++kk)
#pragma unroll
    for (int g = 0; g < 4; ++g)
#pragma unroll
      for (int e = 0; e < 8; ++e)
        cb_frag[(((t * 2 + kk) * 64) + (g * 16 + l15)) * 8 + e] =
            bf16_bits(c[kk * 32 + g * 8 + e]);
}

// --- main: fused distance-GEMM + argmin + loss partial + output write ------
__global__ __launch_bounds__(256) void vq_main(
    const float* __restrict__ x,
    const unsigned short* __restrict__ cb_frag,
    const float* __restrict__ hneg,
    const float* __restrict__ cbT,
    float* __restrict__ out,
    float* __restrict__ partials)
{
  __shared__ float          hneg_lds[KC];      // 4 KB
  __shared__ unsigned short bbuf[2][2048];     // 2 x 4 KB (2 tiles/phase)
  __shared__ float xsq_lds[64];
  __shared__ float sse_lds[64];
  __shared__ int   idx_lds[64];

  const int tid  = threadIdx.x;
  const int wv   = tid >> 6;
  const int lane = tid & 63;
  const int l15  = lane & 15;
  const int g    = lane >> 4;

  const int row = blockIdx.x;            // global (b,h) row, 0..2047
  const int b   = row >> 6;
  const int h   = row & 63;
  const float* xb = x + (size_t)b * DD * HHWW + h * 64;  // xb[d*4096 + w]

  // ---- stage hneg (4 KB) + phase 0 of B (4 KB) into LDS ----
  gload_lds16((const char*)hneg + wv * 1024 + lane * 16,
              (char*)hneg_lds + wv * 1024);
  gload_lds16((const char*)cb_frag + wv * 1024 + lane * 16,
              (char*)bbuf[0] + wv * 1024);

  // ---- load A fragments for THIS wave's 16 positions + ||x||^2 ----
  // A layout (matches B): row i = lane&15, k = kk*32 + (lane>>4)*8 + e.
  const int w = wv * 16 + l15;           // position within row
  bf16x8 afrag[2];
  {
    float s = 0.f;
#pragma unroll
    for (int kk = 0; kk < 2; ++kk) {
      const int dbase = kk * 32 + g * 8;
      u16x8 f;
#pragma unroll
      for (int e = 0; e < 8; ++e) {
        float v = xb[(size_t)(dbase + e) * HHWW + w];
        s += v * v;
        f[e] = bf16_bits(v);
      }
      afrag[kk] = __builtin_bit_cast(bf16x8, f);
    }
    s += __shfl_xor(s, 16, 64);
    s += __shfl_xor(s, 32, 64);
    if (g == 0) xsq_lds[w] = s;          // full 64-dim ||x||^2
  }

  __syncthreads();                       // staged data + xsq ready

  // ---- scan 64 code tiles: 32 phases x 2 tiles, double-buffered ----
  float best_s[4];
  int   best_c[4];
#pragma unroll
  for (int r = 0; r < 4; ++r) { best_s[r] = -FLT_MAX; best_c[r] = 0; }

  int cur = 0;
  for (int ph = 0; ph < 32; ++ph) {
    if (ph < 31)                         // prefetch next phase (other buffer)
      gload_lds16((const char*)cb_frag + (ph + 1) * 4096 + wv * 1024 + lane * 16,
                  (char*)bbuf[cur ^ 1] + wv * 1024);
#pragma unroll
    for (int t = 0; t < 2; ++t) {
      const int tc = ph * 2 + t;
      const float mh = hneg_lds[tc * 16 + l15];   // folded into C-init
      const bf16x8* bp = (const bf16x8*)(&bbuf[cur][t * 1024]);
      const bf16x8 b0 = bp[lane];        // kk=0, ds_read_b128 (conflict-free)
      const bf16x8 b1 = bp[64 + lane];   // kk=1
      f32x4 acc = {mh, mh, mh, mh};
      acc = __builtin_amdgcn_mfma_f32_16x16x32_bf16(afrag[0], b0, acc, 0, 0, 0);
      acc = __builtin_amdgcn_mfma_f32_16x16x32_bf16(afrag[1], b1, acc, 0, 0, 0);
      const int code = tc * 16 + l15;
#pragma unroll
      for (int r = 0; r < 4; ++r) {      // C/D: col=lane&15(code), row=g*4+r(pos)
        float v = acc[r];
        if (v > best_s[r]) { best_s[r] = v; best_c[r] = code; }
      }
    }
    __syncthreads();                     // drains prefetch + ds reads
    cur ^= 1;
  }

  // ---- cross-lane argmax over the 16 code columns (lane&15) ----
#pragma unroll
  for (int r = 0; r < 4; ++r) {
    float s = best_s[r];
    int   c = best_c[r];
#pragma unroll
    for (int m = 1; m < 16; m <<= 1) {
      float so = __shfl_xor(s, m, 64);
      int   co = __shfl_xor(c, m, 64);
      if (so > s || (so == s && co < c)) { s = so; c = co; }
    }
    if (l15 == 0) {
      const int p = wv * 16 + g * 4 + r;   // global position in row
      idx_lds[p] = c;
      sse_lds[p] = xsq_lds[p] - 2.0f * s;
    }
  }

  __syncthreads();

  // ---- block loss partial ----
  if (tid < 64) {
    float t = sse_lds[tid];
#pragma unroll
    for (int m = 1; m < 64; m <<= 1) t += __shfl_xor(t, m, 64);
    if (tid == 0) partials[blockIdx.x] = t;
  }

  // ---- write quantized output (transposed, d-rows split across waves) ----
  const int myidx = idx_lds[lane];       // position w = lane
  float* ob = out + (size_t)b * DD * HHWW + h * 64;
#pragma unroll
  for (int dd = 0; dd < 16; ++dd) {
    const int d = wv * 16 + dd;
    ob[(size_t)d * HHWW + lane] = cbT[d * KC + myidx];
  }
}

// --- final loss reduce ------------------------------------------------------
__global__ __launch_bounds__(256) void vq_loss(
    const float* __restrict__ partials, float* __restrict__ loss_out)
{
  __shared__ float sred[4];
  int tid = threadIdx.x;
  float s = 0.f;
  for (int i = tid; i < NBLK; i += 256) s += partials[i];
#pragma unroll
  for (int m = 1; m < 64; m <<= 1) s += __shfl_xor(s, m, 64);
  if ((tid & 63) == 0) sred[tid >> 6] = s;
  __syncthreads();
  if (tid == 0)
    loss_out[0] = (sred[0] + sred[1] + sred[2] + sred[3]) * (1.25f / NPOSD);
}

extern "C" void kernel_launch(void* const* d_in, const int* in_sizes, int n_in,
                              void* d_out, int out_size, void* d_ws, size_t ws_size,
                              hipStream_t stream) {
  const float* x  = (const float*)d_in[0];
  const float* cb = (const float*)d_in[1];
  float* out      = (float*)d_out;
  float* loss_out = out + 8388608;

  char* ws = (char*)d_ws;
  unsigned short* cb_frag = (unsigned short*)(ws);      // 131072 B
  float* hneg     = (float*)(ws + 131072);              //   4096 B
  float* cbT      = (float*)(ws + 135168);              // 262144 B
  float* partials = (float*)(ws + 397312);              //   8192 B

  vq_pre <<<4,    256, 0, stream>>>(cb, cb_frag, hneg, cbT);
  vq_main<<<NBLK, 256, 0, stream>>>(x, cb_frag, hneg, cbT, out, partials);
  vq_loss<<<1,    256, 0, stream>>>(partials, loss_out);
}

// Round 5
// 59.113 us; speedup vs baseline: 4.0371x; 1.0152x over previous
//
#include <hip/hip_runtime.h>
#include <cfloat>

// ---------------------------------------------------------------------------
// VQ-VAE vector quantizer forward (MI355X / gfx950)
//   x        [32][64][64][64] f32   (B, D, H, W)
//   codebook [1024][64] f32
// out: x_q transposed back to [B,D,H,W] (8388608 f32)  +  loss scalar (1 f32)
//
// argmin_k ||x - c_k||^2  ==  argmax_k (x . c_k - ||c_k||^2/2)
// loss = 1.25 * mean(||x - c_idx||^2) ; SSE(pos) = ||x||^2 - 2*(score-1)
//
// R5 = R4 with the tile-stride bug fixed: cb_frag tile = 2048 B (not 4096),
// kk=1 half at +1024 B (not +2048). R4's waves 2-3 read past cb_frag into
// hneg1/poison -> +/-Inf products -> NaN loss.
//
// Structure: block = one (b,h) row (64 positions), 4 waves K-split the 1024
// codes (256 each). B-fragments read DIRECTLY from L2 into registers
// (cb_frag = 128 KB, L2-resident; no LDS staging, no main-loop barriers).
// Argmax via packed sortable u32: scores shifted to ~[0.95,1.05] via
// C-init = 1 - ||c||^2/2, packed = (bits & ~1023) | (1023-code),
// merged with v_and_or + v_max_u32 (2 VALU ops/element).
// ---------------------------------------------------------------------------

#define DD   64
#define HHWW 4096          // H*W
#define KC   1024
#define NBLK  2048         // one block per (b,h) row
#define NPOSD 8388608.0f   // N * D

typedef __bf16  bf16x8 __attribute__((ext_vector_type(8)));
typedef unsigned short u16x8 __attribute__((ext_vector_type(8)));
typedef float   f32x4  __attribute__((ext_vector_type(4)));

__device__ __forceinline__ unsigned short bf16_bits(float f) {
  unsigned u = __float_as_uint(f);
  return (unsigned short)((u + 0x7FFFu + ((u >> 16) & 1u)) >> 16);  // RNE
}

// global->LDS direct copy, 16B per lane. ldst wave-uniform; HW adds lane*16.
__device__ __forceinline__ void gload_lds16(const void* gsrc, void* ldst) {
  __builtin_amdgcn_global_load_lds(
      (const __attribute__((address_space(1))) unsigned int*)gsrc,
      (__attribute__((address_space(3))) unsigned int*)ldst, 16, 0, 0);
}

// --- precompute: fragment-ordered bf16 codebook + (1 - ||c||^2/2) ----------
__global__ __launch_bounds__(256) void vq_pre(
    const float* __restrict__ cb,          // [1024][64]
    unsigned short* __restrict__ cb_frag,  // [tile=64][kk=2][lane=64][e=8]
    float* __restrict__ hneg1)             // [1024] : 1 - ||c||^2/2
{
  int k = blockIdx.x * 256 + threadIdx.x;
  if (k >= KC) return;
  float c[DD];
  float sum = 0.f;
#pragma unroll
  for (int d = 0; d < DD; ++d) { c[d] = cb[k * DD + d]; sum += c[d] * c[d]; }
  hneg1[k] = 1.0f - 0.5f * sum;
  int t = k >> 4, l15 = k & 15;
#pragma unroll
  for (int kk = 0; kk < 2; ++kk)
#pragma unroll
    for (int g = 0; g < 4; ++g)
#pragma unroll
      for (int e = 0; e < 8; ++e)
        cb_frag[(((t * 2 + kk) * 64) + (g * 16 + l15)) * 8 + e] =
            bf16_bits(c[kk * 32 + g * 8 + e]);
}

// --- main: fused distance-GEMM + argmin + loss partial + output write ------
__global__ __launch_bounds__(256) void vq_main(
    const float* __restrict__ x,
    const unsigned short* __restrict__ cb_frag,
    const float* __restrict__ hneg1,
    const float* __restrict__ cb,
    float* __restrict__ out,
    float* __restrict__ partials)
{
  __shared__ float        hneg_lds[KC];   // 4 KB
  __shared__ unsigned int cand[4][64];    // 1 KB per-wave winners
  __shared__ int          idx_lds[64];

  const int tid  = threadIdx.x;
  const int wv   = tid >> 6;
  const int lane = tid & 63;
  const int l15  = lane & 15;
  const int g    = lane >> 4;

  const int row = blockIdx.x;            // global (b,h) row, 0..2047
  const int b   = row >> 6;
  const int h   = row & 63;
  const float* xb = x + (size_t)b * DD * HHWW + h * 64;  // xb[d*4096 + w]

  // ---- stage hneg1 (4 KB) into LDS (one instr per thread) ----
  gload_lds16((const char*)hneg1 + (size_t)tid * 16, (char*)hneg_lds + wv * 1024);

  // ---- A fragments for the row's 64 positions (all 4 waves identical:
  //      same addresses -> L1-served) + per-position ||x||^2 ----
  // A layout (matches B): row i = lane&15, k = kk*32 + (lane>>4)*8 + e.
  bf16x8 afrag[4][2];
  float  xsq[4];
#pragma unroll
  for (int pt = 0; pt < 4; ++pt) {
    const int w = pt * 16 + l15;
    float s = 0.f;
#pragma unroll
    for (int kk = 0; kk < 2; ++kk) {
      const int dbase = kk * 32 + g * 8;
      u16x8 f;
#pragma unroll
      for (int e = 0; e < 8; ++e) {
        float v = xb[(size_t)(dbase + e) * HHWW + w];
        s += v * v;
        f[e] = bf16_bits(v);
      }
      afrag[pt][kk] = __builtin_bit_cast(bf16x8, f);
    }
    s += __shfl_xor(s, 16, 64);
    s += __shfl_xor(s, 32, 64);
    xsq[pt] = s;                         // full 64-dim ||x||^2, every lane
  }

  __syncthreads();                       // hneg_lds ready

  // ---- this wave's 16 code tiles (codes wv*256 .. wv*256+255) ----
  // best = packed (score_bits & ~1023) | (1023-code); score ~ [0.95,1.05] > 0
  // so bit pattern is monotone; ties prefer LOWER code (argmin semantics).
  unsigned int best[4][4];
#pragma unroll
  for (int pt = 0; pt < 4; ++pt)
#pragma unroll
    for (int r = 0; r < 4; ++r) best[pt][r] = 0u;

  const unsigned int MASK = 0xFFFFFC00u;
  const int codec0 = 1023 - wv * 256 - l15;
  // cb_frag tile stride = 2048 B ([kk=2][lane=64][16B]); wave chunk = 16 tiles.
  const char* bb = (const char*)cb_frag + (size_t)wv * 16 * 2048 + (size_t)lane * 16;

  bf16x8 nb0 = *(const bf16x8*)(bb);          // depth-1 prefetch (kk=0)
  bf16x8 nb1 = *(const bf16x8*)(bb + 1024);   // kk=1

#pragma unroll 4
  for (int t = 0; t < 16; ++t) {
    const bf16x8 b0 = nb0, b1 = nb1;
    const char* bn = bb + (size_t)(((t + 1) & 15) * 2048);
    nb0 = *(const bf16x8*)(bn);
    nb1 = *(const bf16x8*)(bn + 1024);

    const float mh1 = hneg_lds[wv * 256 + t * 16 + l15];  // 1 - ||c||^2/2
    const unsigned int codec = (unsigned int)(codec0 - t * 16);

    f32x4 acc[4];
#pragma unroll
    for (int pt = 0; pt < 4; ++pt) acc[pt] = (f32x4){mh1, mh1, mh1, mh1};
#pragma unroll
    for (int pt = 0; pt < 4; ++pt)
      acc[pt] = __builtin_amdgcn_mfma_f32_16x16x32_bf16(afrag[pt][0], b0, acc[pt], 0, 0, 0);
#pragma unroll
    for (int pt = 0; pt < 4; ++pt)
      acc[pt] = __builtin_amdgcn_mfma_f32_16x16x32_bf16(afrag[pt][1], b1, acc[pt], 0, 0, 0);

#pragma unroll
    for (int pt = 0; pt < 4; ++pt)
#pragma unroll
      for (int r = 0; r < 4; ++r) {      // C/D: col=lane&15(code), row=g*4+r(pos)
        unsigned int p = (__float_as_uint(acc[pt][r]) & MASK) | codec;
        best[pt][r] = best[pt][r] > p ? best[pt][r] : p;
      }
  }

  // ---- cross-lane max over the 16 code columns (lane&15) ----
#pragma unroll
  for (int pt = 0; pt < 4; ++pt)
#pragma unroll
    for (int r = 0; r < 4; ++r) {
      unsigned int v = best[pt][r];
#pragma unroll
      for (int m = 1; m < 16; m <<= 1) {
        unsigned int vo = __shfl_xor(v, m, 64);
        v = v > vo ? v : vo;
      }
      if (l15 == 0) cand[wv][pt * 16 + g * 4 + r] = v;
    }

  __syncthreads();

  // ---- wave 0: merge the 4 K-split candidates, loss partial ----
  if (tid < 64) {
    unsigned int v01 = cand[0][tid] > cand[1][tid] ? cand[0][tid] : cand[1][tid];
    unsigned int v23 = cand[2][tid] > cand[3][tid] ? cand[2][tid] : cand[3][tid];
    unsigned int v   = v01 > v23 ? v01 : v23;
    idx_lds[tid] = 1023 - (int)(v & 1023u);
    const float vt = __uint_as_float(v & MASK);     // score + 1 (truncated)
    const int ptt = tid >> 4;                       // xsq[pt] select (static)
    float xq = xsq[0];
    if (ptt == 1) xq = xsq[1];
    if (ptt == 2) xq = xsq[2];
    if (ptt == 3) xq = xsq[3];
    float sse = __builtin_fmaf(vt, -2.0f, xq + 2.0f);
#pragma unroll
    for (int m = 1; m < 64; m <<= 1) sse += __shfl_xor(sse, m, 64);
    if (tid == 0) partials[blockIdx.x] = sse;
  }

  __syncthreads();

  // ---- write quantized output; gather from row-major cb (16 KB working
  //      set per block -> L1-hit after first touch) ----
  const int myidx = idx_lds[lane];       // position w = lane
  const float* crow = cb + (size_t)myidx * DD;
  float* ob = out + (size_t)b * DD * HHWW + h * 64;
#pragma unroll
  for (int dd = 0; dd < 16; ++dd) {
    const int d = wv * 16 + dd;
    ob[(size_t)d * HHWW + lane] = crow[d];
  }
}

// --- final loss reduce ------------------------------------------------------
__global__ __launch_bounds__(256) void vq_loss(
    const float* __restrict__ partials, float* __restrict__ loss_out)
{
  __shared__ float sred[4];
  int tid = threadIdx.x;
  float s = 0.f;
  for (int i = tid; i < NBLK; i += 256) s += partials[i];
#pragma unroll
  for (int m = 1; m < 64; m <<= 1) s += __shfl_xor(s, m, 64);
  if ((tid & 63) == 0) sred[tid >> 6] = s;
  __syncthreads();
  if (tid == 0)
    loss_out[0] = (sred[0] + sred[1] + sred[2] + sred[3]) * (1.25f / NPOSD);
}

extern "C" void kernel_launch(void* const* d_in, const int* in_sizes, int n_in,
                              void* d_out, int out_size, void* d_ws, size_t ws_size,
                              hipStream_t stream) {
  const float* x  = (const float*)d_in[0];
  const float* cb = (const float*)d_in[1];
  float* out      = (float*)d_out;
  float* loss_out = out + 8388608;

  char* ws = (char*)d_ws;
  unsigned short* cb_frag = (unsigned short*)(ws);      // 131072 B
  float* hneg1    = (float*)(ws + 131072);              //   4096 B
  float* partials = (float*)(ws + 135168);              //   8192 B

  vq_pre <<<4,    256, 0, stream>>>(cb, cb_frag, hneg1);
  vq_main<<<NBLK, 256, 0, stream>>>(x, cb_frag, hneg1, cb, out, partials);
  vq_loss<<<1,    256, 0, stream>>>(partials, loss_out);
}